// Round 10
// baseline (1154.378 us; speedup 1.0000x reference)
//
#include <hip/hip_runtime.h>
#include <hip/hip_bf16.h>
#include <math.h>

#define B_ 16
#define C_ 512
#define T_ 4096
#define I_ 1536

typedef short short8 __attribute__((ext_vector_type(8)));
typedef unsigned short ushort8 __attribute__((ext_vector_type(8)));
typedef unsigned short us4 __attribute__((ext_vector_type(4)));
typedef float f32x4 __attribute__((ext_vector_type(4)));
typedef int i32x4 __attribute__((ext_vector_type(4)));
typedef char char8v __attribute__((ext_vector_type(8)));

static __device__ __forceinline__ unsigned short f2bf(float f) {
  union { float f; unsigned int u; } v; v.f = f;
  unsigned int r = v.u + 0x7fffu + ((v.u >> 16) & 1u);
  return (unsigned short)(r >> 16);
}
static __device__ __forceinline__ float bf2f(unsigned short h) {
  union { unsigned int u; float f; } v; v.u = ((unsigned int)h) << 16;
  return v.f;
}

// tanh-form GELU (branchless). |err vs erf-GELU| <= ~3e-3/elem, diluted by @W2.
static __device__ __forceinline__ float gelu_f(float v) {
  const float v2 = v * v;
  const float w = v * (0.7978845608f + 0.0356774081f * v2);
  const float a = fminf(w * 2.8853900818f, 126.0f);
  const float u = exp2f(a);
  return v * u / (u + 1.0f);
}

static __device__ __forceinline__ char q8(float v, float inv) {
  int q = __float2int_rn(v * inv);
  q = q > 127 ? 127 : (q < -127 ? -127 : q);
  return (char)q;
}

__device__ __forceinline__ void gload_lds16(const void* g, void* l) {
  __builtin_amdgcn_global_load_lds((const __attribute__((address_space(1))) void*)g,
                                   (__attribute__((address_space(3))) void*)l, 16, 0, 0);
}

#define H1S   (3.0f / 127.0f)
#define IH1S  (127.0f / 3.0f)

// ---------------- tiny precompute kernels ----------------

__global__ __launch_bounds__(256) void pre_kv(const float* __restrict__ aux,
                                              const float* __restrict__ Wkv,
                                              const float* __restrict__ bkv,
                                              float* __restrict__ kv) {
  const int g = blockIdx.x * 256 + threadIdx.x;   // 65536 = 64 * 1024
  const int j = g >> 10, cc = g & 1023;
  float s = bkv[cc];
  for (int i = 0; i < C_; ++i) s += aux[j * C_ + i] * Wkv[i * (2 * C_) + cc];
  kv[g] = s;
}

// col = h*64 + j  (softmax-contiguous layout)
__global__ __launch_bounds__(256) void pre_MT(const float* __restrict__ Wq,
                                              const float* __restrict__ bq,
                                              const float* __restrict__ kv,
                                              unsigned short* __restrict__ MT,
                                              float* __restrict__ cbias) {
  const int col = blockIdx.x;                 // 0..511
  const int h = col >> 6, j = col & 63;
  const float* kvp = kv + j * 1024 + h * 64;
  for (int c = threadIdx.x; c < C_; c += 256) {
    float s = 0.f;
    for (int d = 0; d < 64; ++d) s += Wq[(size_t)c * C_ + h * 64 + d] * kvp[d];
    MT[(size_t)col * C_ + c] = f2bf(0.125f * s);   // scale^2 = (C/H)^-0.5
  }
  if (threadIdx.x == 0) {
    float s = 0.f;
    for (int d = 0; d < 64; ++d) s += bq[h * 64 + d] * kvp[d];
    cbias[col] = 0.125f * s;
  }
}

__global__ __launch_bounds__(256) void pre_VoT(const float* __restrict__ Wo,
                                               const float* __restrict__ kv,
                                               unsigned short* __restrict__ VoT) {
  const int cp = blockIdx.x;                  // output channel
  for (int col = threadIdx.x; col < 512; col += 256) {
    const int h = col >> 6, j = col & 63;
    float s = 0.f;
    for (int d = 0; d < 64; ++d)
      s += kv[j * 1024 + 512 + h * 64 + d] * Wo[(size_t)(h * 64 + d) * C_ + cp];
    VoT[(size_t)cp * 512 + col] = f2bf(s);
  }
}

// per-output-col absmax scales for W1 / W2 (coalesced reads)
__global__ __launch_bounds__(256) void pre_w1s(const float* __restrict__ W1,
                                               float* __restrict__ w1s) {
  const int n = blockIdx.x * 256 + threadIdx.x;    // 0..1535
  float amax = 0.f;
  for (int k = 0; k < 512; ++k) amax = fmaxf(amax, fabsf(W1[(size_t)k * I_ + n]));
  w1s[n] = fmaxf(amax, 1e-20f) / 127.0f;
}

__global__ __launch_bounds__(256) void pre_w2s(const float* __restrict__ W2,
                                               float* __restrict__ w2s) {
  const int n = blockIdx.x * 256 + threadIdx.x;    // 0..511
  float amax = 0.f;
  for (int k = 0; k < 1536; ++k) amax = fmaxf(amax, fabsf(W2[(size_t)k * C_ + n]));
  w2s[n] = fmaxf(amax, 1e-20f) / 127.0f;
}

__global__ __launch_bounds__(256) void pre_W1Q(const float* __restrict__ W1,
                                               const float* __restrict__ w1s,
                                               char* __restrict__ W1Q) {
  const int g = blockIdx.x * 256 + threadIdx.x;    // 1536*512
  const int n = g >> 9, k = g & 511;
  W1Q[g] = q8(W1[(size_t)k * I_ + n], 1.0f / w1s[n]);
}

__global__ __launch_bounds__(256) void pre_W2Q(const float* __restrict__ W2,
                                               const float* __restrict__ w2s,
                                               char* __restrict__ W2Q) {
  const int g = blockIdx.x * 256 + threadIdx.x;    // 512*1536
  const int n = g / 1536, k = g - n * 1536;
  W2Q[g] = q8(W2[(size_t)k * C_ + n], 1.0f / w2s[n]);
}

// ---------------- x (B,C,T) -> xt bf16 (B*T, C) ----------------

__global__ __launch_bounds__(256) void xt_kernel(const float* __restrict__ x,
                                                 unsigned short* __restrict__ xt) {
  __shared__ float ld[64][65];
  const int tid = threadIdx.x;
  const int t0 = blockIdx.x * 64, c0 = blockIdx.y * 64, b = blockIdx.z;
  for (int idx = tid; idx < 4096; idx += 256) {
    const int r = idx >> 6, cc = idx & 63;
    ld[r][cc] = x[((size_t)(b * C_ + c0 + r)) * T_ + t0 + cc];
  }
  __syncthreads();
  for (int idx = tid; idx < 4096; idx += 256) {
    const int tr = idx >> 6, cl = idx & 63;
    xt[((size_t)(b * T_ + t0 + tr)) * C_ + c0 + cl] = f2bf(ld[cl][tr]);
  }
}

// ---------------- GEMM A (m97 structure, k-major LDS chunks): attention GEMMs ----------------
// EPI 1: per-head softmax epilogue -> outU (P bf16, stride N). bias = cb.
// EPI 4: rs[(b*C+c)*T+t] = bf16( bf2f(resU[r*512+c]) + acc + bias[c] )   (resU = xt)
template<int N, int K, int NCOL, int EPI>
__global__ __launch_bounds__(256) void gemm_mfma(const unsigned short* __restrict__ A,
                                                 const unsigned short* __restrict__ Bt,
                                                 const float* __restrict__ bias,
                                                 unsigned short* __restrict__ outU,
                                                 const unsigned short* __restrict__ resU,
                                                 float* __restrict__ outF) {
  __shared__ __align__(16) unsigned short lA[128 * 32];
  __shared__ __align__(16) unsigned short lB[128 * 32];
  const int q = gridDim.x >> 3;
  const int wgid = (blockIdx.x & 7) * q + (blockIdx.x >> 3);
  const int row0 = (wgid / NCOL) * 128;
  const int col0 = (wgid % NCOL) * 128;
  const int tid = threadIdx.x;
  const int w = tid >> 6, lane = tid & 63;
  const int wr = (w >> 1) * 64, wc = (w & 1) * 64;
  const int c1 = tid, c2 = tid + 256;

  const f32x4 zero4 = {0.f, 0.f, 0.f, 0.f};
  f32x4 acc[4][4];
#pragma unroll
  for (int m = 0; m < 4; ++m)
#pragma unroll
    for (int n = 0; n < 4; ++n) acc[m][n] = zero4;

  const size_t aBase = (size_t)row0 * K;
  const size_t bBase = (size_t)col0 * K;
  const int lrow = lane & 15, lg = lane >> 4;

  for (int k0 = 0; k0 < K; k0 += 32) {
    gload_lds16(A + aBase + (size_t)(c1 & 127) * K + k0 + (c1 >> 7) * 8, (char*)lA + c1 * 16);
    gload_lds16(A + aBase + (size_t)(c2 & 127) * K + k0 + (c2 >> 7) * 8, (char*)lA + c2 * 16);
    gload_lds16(Bt + bBase + (size_t)(c1 & 127) * K + k0 + (c1 >> 7) * 8, (char*)lB + c1 * 16);
    gload_lds16(Bt + bBase + (size_t)(c2 & 127) * K + k0 + (c2 >> 7) * 8, (char*)lB + c2 * 16);
    __syncthreads();
    short8 av[4], bv[4];
#pragma unroll
    for (int m = 0; m < 4; ++m)
      av[m] = *(const short8*)&lA[(lg * 128 + wr + m * 16 + lrow) * 8];
#pragma unroll
    for (int n = 0; n < 4; ++n)
      bv[n] = *(const short8*)&lB[(lg * 128 + wc + n * 16 + lrow) * 8];
#pragma unroll
    for (int m = 0; m < 4; ++m)
#pragma unroll
      for (int n = 0; n < 4; ++n)
        acc[m][n] = __builtin_amdgcn_mfma_f32_16x16x32_bf16(av[m], bv[n], acc[m][n], 0, 0, 0);
    __syncthreads();
  }

  if (EPI == 1) {
    float cbv[4];
#pragma unroll
    for (int n = 0; n < 4; ++n) cbv[n] = bias[col0 + wc + n * 16 + lrow];
#pragma unroll
    for (int m = 0; m < 4; ++m) {
#pragma unroll
      for (int i = 0; i < 4; ++i) {
        float e0 = acc[m][0][i] + cbv[0];
        float e1 = acc[m][1][i] + cbv[1];
        float e2 = acc[m][2][i] + cbv[2];
        float e3 = acc[m][3][i] + cbv[3];
        float mx = fmaxf(fmaxf(e0, e1), fmaxf(e2, e3));
        mx = fmaxf(mx, __shfl_xor(mx, 1));
        mx = fmaxf(mx, __shfl_xor(mx, 2));
        mx = fmaxf(mx, __shfl_xor(mx, 4));
        mx = fmaxf(mx, __shfl_xor(mx, 8));
        e0 = __expf(e0 - mx); e1 = __expf(e1 - mx);
        e2 = __expf(e2 - mx); e3 = __expf(e3 - mx);
        float s = e0 + e1 + e2 + e3;
        s += __shfl_xor(s, 1);
        s += __shfl_xor(s, 2);
        s += __shfl_xor(s, 4);
        s += __shfl_xor(s, 8);
        const float inv = 1.0f / s;
        const size_t rb = (size_t)(row0 + wr + m * 16 + (lane >> 4) * 4 + i) * N;
        outU[rb + col0 + wc + 0 * 16 + lrow] = f2bf(e0 * inv);
        outU[rb + col0 + wc + 1 * 16 + lrow] = f2bf(e1 * inv);
        outU[rb + col0 + wc + 2 * 16 + lrow] = f2bf(e2 * inv);
        outU[rb + col0 + wc + 3 * 16 + lrow] = f2bf(e3 * inv);
      }
    }
    return;
  }

#pragma unroll
  for (int m = 0; m < 4; ++m) {
    const int r0 = row0 + wr + m * 16 + ((lane >> 4) << 2);
#pragma unroll
    for (int n = 0; n < 4; ++n) {
      const int c = col0 + wc + n * 16 + lrow;
      const float bb = bias[c];
      const int bidx = r0 >> 12;          // T = 4096
      const int t = r0 & 4095;
      const size_t addr = ((size_t)(bidx * C_ + c)) * T_ + t;
      us4 o;
#pragma unroll
      for (int i = 0; i < 4; ++i)
        o[i] = f2bf(bf2f(resU[(size_t)(r0 + i) * 512 + c]) + acc[m][n][i] + bb);
      *(us4*)&outU[addr] = o;
    }
  }
}

// ---------------- GEMM B: int8 256x256 8-phase (MLP GEMMs), R5 schedule verbatim ----------------
// mfma_i32_16x16x64_i8: K=64/inst, 16-byte frags -> R5's 16B-chunk LDS layout, staging
// lambda and vmcnt accounting unchanged; K-tile = 128 (8 chunks of 16 i8), so phase count
// halves for the same K. acc is exact i32; dequant in epilogue with factored scales.
// EPI 3: H1Q = i8( gelu(acc*rowS[r]*colS[c] + b1[c]) / H1S )
// EPI 5: outF = bf2f(rs) + acc*(H1S*colS[c]) + b2[c]

#define LOAD_AVQ(d, mh) {                                                     \
  const char* abase = lds + ((d)*32768 + (mh)*16384);                         \
  _Pragma("unroll")                                                           \
  for (int ks = 0; ks < 2; ++ks) {                                            \
    const int kc = ks * 4 + lg;                                               \
    _Pragma("unroll")                                                         \
    for (int mf = 0; mf < 4; ++mf)                                            \
      av[ks][mf] = *(const i32x4*)(abase + (size_t)(kc*128 + wm*64 + mf*16 + lrow)*16); \
  } }

#define LOAD_BVQ(d, nh, DST) {                                                \
  const char* bbase = lds + (65536 + (d)*32768 + (nh)*16384);                 \
  _Pragma("unroll")                                                           \
  for (int ks = 0; ks < 2; ++ks) {                                            \
    const int kc = ks * 4 + lg;                                               \
    _Pragma("unroll")                                                         \
    for (int nf = 0; nf < 2; ++nf)                                            \
      DST[ks][nf] = *(const i32x4*)(bbase + (size_t)(kc*128 + wn*32 + nf*16 + lrow)*16); \
  } }

#define PHXQ(LOADS, STAGE_STMT, VM_STMT, MH, NH, BV) {                        \
  LOADS;                                                                      \
  STAGE_STMT;                                                                 \
  VM_STMT;                                                                    \
  __builtin_amdgcn_s_barrier();                                               \
  __builtin_amdgcn_s_setprio(1);                                              \
  _Pragma("unroll")                                                           \
  for (int mf = 0; mf < 4; ++mf)                                              \
    _Pragma("unroll")                                                         \
    for (int nf = 0; nf < 2; ++nf) {                                          \
      acc[(MH)*4+mf][(NH)*2+nf] = __builtin_amdgcn_mfma_i32_16x16x64_i8(       \
          av[0][mf], BV[0][nf], acc[(MH)*4+mf][(NH)*2+nf], 0, 0, 0);          \
      acc[(MH)*4+mf][(NH)*2+nf] = __builtin_amdgcn_mfma_i32_16x16x64_i8(       \
          av[1][mf], BV[1][nf], acc[(MH)*4+mf][(NH)*2+nf], 0, 0, 0);          \
    }                                                                         \
  __builtin_amdgcn_s_setprio(0);                                              \
  asm volatile("s_waitcnt lgkmcnt(0)" ::: "memory");                          \
  __builtin_amdgcn_s_barrier();                                               \
}

#define NOPS ((void)0)

template<int N, int K, int NCOL, int EPI>
__global__ __launch_bounds__(512, 2) void gemm8q(const char* __restrict__ A,
                                                 const char* __restrict__ Bt,
                                                 const float* __restrict__ rowS,
                                                 const float* __restrict__ colS,
                                                 const float* __restrict__ bias,
                                                 char* __restrict__ outQ,
                                                 const unsigned short* __restrict__ resU,
                                                 float* __restrict__ outF) {
  __shared__ __align__(16) char lds[131072];
  const int tid = threadIdx.x;
  const int w = tid >> 6, lane = tid & 63;
  const int wm = w >> 2, wn = w & 3;
  const int lrow = lane & 15, lg = lane >> 4;
  const int q8g = gridDim.x >> 3;
  const int wgid = (blockIdx.x & 7) * q8g + (blockIdx.x >> 3);
  const int row0 = (wgid / NCOL) * 256;
  const int col0 = (wgid % NCOL) * 256;

  auto stageA = [&](int kt, int h) {
    char* base = lds + ((kt & 1) * 32768 + h * 16384);
    const char* gsrc = A + (size_t)(row0 + h * 128) * K + kt * 128;
#pragma unroll
    for (int s = 0; s < 2; ++s) {
      const int qq = w * 128 + s * 64 + lane;
      gload_lds16(gsrc + (size_t)(qq & 127) * K + (qq >> 7) * 16, base + qq * 16);
    }
  };
  auto stageB = [&](int kt, int h) {
    char* base = lds + (65536 + (kt & 1) * 32768 + h * 16384);
    const char* gsrc = Bt + (size_t)(col0 + h * 128) * K + kt * 128;
#pragma unroll
    for (int s = 0; s < 2; ++s) {
      const int qq = w * 128 + s * 64 + lane;
      gload_lds16(gsrc + (size_t)(qq & 127) * K + (qq >> 7) * 16, base + qq * 16);
    }
  };

  const i32x4 zero4 = {0, 0, 0, 0};
  i32x4 acc[8][4];
#pragma unroll
  for (int m = 0; m < 8; ++m)
#pragma unroll
    for (int n = 0; n < 4; ++n) acc[m][n] = zero4;

  i32x4 av[2][4], bv0[2][2], bv1[2][2];

  const int KT = K / 128;     // G3: 4, G4: 12 (both even)

  // prologue: tile0 fully, tile1 halves A0,B0
  stageA(0, 0); stageA(0, 1); stageB(0, 0); stageB(0, 1);
  stageA(1, 0); stageB(1, 0);
  asm volatile("s_waitcnt vmcnt(4)" ::: "memory");
  __builtin_amdgcn_s_barrier();

  for (int i = 0; i < KT / 2; ++i) {
    const int t1 = 2 * i + 1, t2 = 2 * i + 2, t3 = 2 * i + 3;
    // tile 2i (buf 0)
    PHXQ(LOAD_AVQ(0, 0); LOAD_BVQ(0, 0, bv0), { stageA(t1, 1); }, NOPS, 0, 0, bv0);
    PHXQ(LOAD_BVQ(0, 1, bv1),                 { stageB(t1, 1); }, NOPS, 0, 1, bv1);
    PHXQ(LOAD_AVQ(0, 1),                      { if (t2 < KT) stageA(t2, 0); }, NOPS, 1, 1, bv1);
    PHXQ(NOPS,                                { if (t2 < KT) stageB(t2, 0); },
        { if (t2 < KT) { asm volatile("s_waitcnt vmcnt(4)" ::: "memory"); }
          else         { asm volatile("s_waitcnt vmcnt(0)" ::: "memory"); } },
        1, 0, bv0);
    // tile 2i+1 (buf 1)
    PHXQ(LOAD_AVQ(1, 0); LOAD_BVQ(1, 0, bv0), { if (t2 < KT) stageA(t2, 1); }, NOPS, 0, 0, bv0);
    PHXQ(LOAD_BVQ(1, 1, bv1),                 { if (t2 < KT) stageB(t2, 1); }, NOPS, 0, 1, bv1);
    PHXQ(LOAD_AVQ(1, 1),                      { if (t3 < KT) stageA(t3, 0); }, NOPS, 1, 1, bv1);
    PHXQ(NOPS,                                { if (t3 < KT) stageB(t3, 0); },
        { asm volatile("s_waitcnt vmcnt(4)" ::: "memory"); },
        1, 0, bv0);
  }

  // epilogue
#pragma unroll
  for (int mf = 0; mf < 8; ++mf) {
    const int r0 = row0 + (mf >> 2) * 128 + wm * 64 + (mf & 3) * 16 + lg * 4;
#pragma unroll
    for (int nf = 0; nf < 4; ++nf) {
      const int c = col0 + (nf >> 1) * 128 + wn * 32 + (nf & 1) * 16 + lrow;
      const float bb = bias[c];
      const float sc = colS[c];
      if (EPI == 3) {
#pragma unroll
        for (int i = 0; i < 4; ++i) {
          const float v = (float)acc[mf][nf][i] * (rowS[r0 + i] * sc) + bb;
          const float g = gelu_f(v);
          outQ[(size_t)(r0 + i) * N + c] = q8(fminf(fmaxf(g, -3.0f), 3.0f), IH1S);
        }
      } else {  // EPI == 5
        const float ds = H1S * sc;
        const int bidx = r0 >> 12;
        const int t = r0 & 4095;
        const size_t addr = ((size_t)(bidx * C_ + c)) * T_ + t;
        const us4 rv = *(const us4*)&resU[addr];
        f32x4 o;
#pragma unroll
        for (int i = 0; i < 4; ++i) o[i] = bf2f(rv[i]) + (float)acc[mf][nf][i] * ds + bb;
        *(f32x4*)&outF[addr] = o;
      }
    }
  }
}

// ---------------- fused conv1d(k=7,p=3) + AdaLayerNorm -> int8 yln + per-token scale ----------------

__global__ __launch_bounds__(256) void convq_kernel(
    const unsigned short* __restrict__ rs,
    const float* __restrict__ dww,
    const float* __restrict__ dwb,
    const int* __restrict__ ids,
    const float* __restrict__ sce,
    const float* __restrict__ she,
    char* __restrict__ ylnq,
    float* __restrict__ yscale) {
  __shared__ float cbuf[16 * 520];
  const int tid = threadIdx.x;
  const int t0 = blockIdx.x * 16;
  const int b = blockIdx.y;
#pragma unroll
  for (int cc = 0; cc < 2; ++cc) {
    const int c = cc * 256 + tid;
    float f[24];
#pragma unroll
    for (int j = 0; j < 6; ++j) {
      const int t = t0 - 4 + j * 4;
      if (t >= 0 && t < T_) {
        const us4 v = *(const us4*)&rs[((size_t)(b * C_ + c)) * T_ + t];
#pragma unroll
        for (int i = 0; i < 4; ++i) f[j * 4 + i] = bf2f(v[i]);
      } else {
#pragma unroll
        for (int i = 0; i < 4; ++i) f[j * 4 + i] = 0.f;
      }
    }
    float wk[7];
#pragma unroll
    for (int k = 0; k < 7; ++k) wk[k] = dww[c * 7 + k];
    const float bb = dwb[c];
#pragma unroll
    for (int tt = 0; tt < 16; ++tt) {
      float s = bb;
#pragma unroll
      for (int k = 0; k < 7; ++k) s += f[tt + 1 + k] * wk[k];
      cbuf[tt * 520 + c] = s;
    }
  }
  __syncthreads();
  const int lane = tid & 63, w = tid >> 6;
  const int id = ids[b];
#pragma unroll
  for (int tt = 0; tt < 4; ++tt) {
    const int t = w * 4 + tt;
    const f32x4 v0 = *(const f32x4*)&cbuf[t * 520 + lane * 8];
    const f32x4 v1 = *(const f32x4*)&cbuf[t * 520 + lane * 8 + 4];
    float s = 0.f, sq = 0.f;
#pragma unroll
    for (int i = 0; i < 4; ++i) { s += v0[i]; sq += v0[i] * v0[i]; }
#pragma unroll
    for (int i = 0; i < 4; ++i) { s += v1[i]; sq += v1[i] * v1[i]; }
#pragma unroll
    for (int off = 1; off < 64; off <<= 1) {
      s += __shfl_xor(s, off);
      sq += __shfl_xor(sq, off);
    }
    const float mean = s * (1.0f / 512.0f);
    const float var = sq * (1.0f / 512.0f) - mean * mean;
    const float rstd = rsqrtf(var + 1e-6f);
    const f32x4 sc0 = *(const f32x4*)&sce[id * C_ + lane * 8];
    const f32x4 sc1 = *(const f32x4*)&sce[id * C_ + lane * 8 + 4];
    const f32x4 sh0 = *(const f32x4*)&she[id * C_ + lane * 8];
    const f32x4 sh1 = *(const f32x4*)&she[id * C_ + lane * 8 + 4];
    float y[8];
    float amax = 0.f;
#pragma unroll
    for (int i = 0; i < 4; ++i) {
      y[i]     = (v0[i] - mean) * rstd * sc0[i] + sh0[i];
      y[4 + i] = (v1[i] - mean) * rstd * sc1[i] + sh1[i];
    }
#pragma unroll
    for (int i = 0; i < 8; ++i) amax = fmaxf(amax, fabsf(y[i]));
#pragma unroll
    for (int off = 1; off < 64; off <<= 1) amax = fmaxf(amax, __shfl_xor(amax, off));
    amax = fmaxf(amax, 1e-20f);
    const float inv = 127.0f / amax;
    const int tg = b * T_ + t0 + t;
    char8v o;
#pragma unroll
    for (int i = 0; i < 8; ++i) o[i] = q8(y[i], inv);
    *(char8v*)&ylnq[(size_t)tg * C_ + lane * 8] = o;
    if (lane == 0) yscale[tg] = amax * (1.0f / 127.0f);
  }
}

// ---------------- launch ----------------

extern "C" void kernel_launch(void* const* d_in, const int* in_sizes, int n_in,
                              void* d_out, int out_size, void* d_ws, size_t ws_size,
                              hipStream_t stream) {
  const float* x   = (const float*)d_in[0];
  const int*   ids = (const int*)d_in[1];
  const float* Wq  = (const float*)d_in[2];
  const float* bq  = (const float*)d_in[3];
  const float* Wkv = (const float*)d_in[4];
  const float* bkv = (const float*)d_in[5];
  const float* Wo  = (const float*)d_in[6];
  const float* bo  = (const float*)d_in[7];
  const float* dww = (const float*)d_in[8];
  const float* dwb = (const float*)d_in[9];
  const float* sce = (const float*)d_in[10];
  const float* she = (const float*)d_in[11];
  const float* W1  = (const float*)d_in[12];
  const float* b1  = (const float*)d_in[13];
  const float* W2  = (const float*)d_in[14];
  const float* b2  = (const float*)d_in[15];
  const float* aux = (const float*)d_in[16];
  float* out = (float*)d_out;

  char* ws = (char*)d_ws;
  unsigned short* xt   = (unsigned short*)(ws + 0);              // 64 MB
  unsigned short* P    = (unsigned short*)(ws + (64u  << 20));   // 64 MB
  char*           ylnq = (char*)(ws + (64u << 20));              // 32 MB (overlays P; P dead)
  float*          ysc  = (float*)(ws + (100u << 20));            // 256 KB
  unsigned short* rs   = (unsigned short*)(ws + (128u << 20));   // 64 MB (bf16)
  char*           H1Q  = (char*)(ws + (192u << 20));             // 96 MB (i8)
  char* sm = ws + (384u << 20);
  float*          kv   = (float*)(sm);                           // 256 KB
  float*          cb   = (float*)(sm + 262144);                  // 2 KB
  unsigned short* MT   = (unsigned short*)(sm + 264192);         // 512 KB
  unsigned short* VoT  = (unsigned short*)(sm + 788480);         // 512 KB
  char*           W1Q  = (char*)(sm + 1312768);                  // 768 KB
  char*           W2Q  = (char*)(sm + 2099200);                  // 768 KB
  float*          w1s  = (float*)(sm + 2885632);                 // 6 KB
  float*          w2s  = (float*)(sm + 2891776);                 // 2 KB

  pre_kv <<<dim3(256),  dim3(256), 0, stream>>>(aux, Wkv, bkv, kv);
  pre_MT <<<dim3(512),  dim3(256), 0, stream>>>(Wq, bq, kv, MT, cb);
  pre_VoT<<<dim3(512),  dim3(256), 0, stream>>>(Wo, kv, VoT);
  pre_w1s<<<dim3(6),    dim3(256), 0, stream>>>(W1, w1s);
  pre_w2s<<<dim3(2),    dim3(256), 0, stream>>>(W2, w2s);
  pre_W1Q<<<dim3(3072), dim3(256), 0, stream>>>(W1, w1s, W1Q);
  pre_W2Q<<<dim3(3072), dim3(256), 0, stream>>>(W2, w2s, W2Q);
  xt_kernel<<<dim3(64, 8, 16), dim3(256), 0, stream>>>(x, xt);

  // attention as two m97-structure GEMMs with fused softmax / residual epilogues
  gemm_mfma<512, 512, 4, 1><<<dim3(2048), dim3(256), 0, stream>>>(
      xt, MT, cb, P, nullptr, nullptr);
  gemm_mfma<512, 512, 4, 4><<<dim3(2048), dim3(256), 0, stream>>>(
      P, VoT, bo, rs, xt, nullptr);
  convq_kernel<<<dim3(256, 16), dim3(256), 0, stream>>>(rs, dww, dwb, ids, sce, she,
                                                        ylnq, ysc);
  // MLP as two int8 256^2 8-phase GEMMs (R5 schedule, half the phases)
  gemm8q<1536, 512, 6, 3><<<dim3(1536), dim3(512), 0, stream>>>(
      ylnq, W1Q, ysc, w1s, b1, H1Q, nullptr, nullptr);
  gemm8q<512, 1536, 2, 5><<<dim3(512), dim3(512), 0, stream>>>(
      H1Q, W2Q, nullptr, w2s, b2, nullptr, rs, out);
}

// Round 11
// 683.281 us; speedup vs baseline: 1.6895x; 1.6895x over previous
//
#include <hip/hip_runtime.h>
#include <hip/hip_bf16.h>
#include <math.h>

#define B_ 16
#define C_ 512
#define T_ 4096
#define I_ 1536

typedef short short8 __attribute__((ext_vector_type(8)));
typedef unsigned short ushort8 __attribute__((ext_vector_type(8)));
typedef unsigned short us4 __attribute__((ext_vector_type(4)));
typedef float f32x4 __attribute__((ext_vector_type(4)));
typedef int i32x4 __attribute__((ext_vector_type(4)));
typedef char char8v __attribute__((ext_vector_type(8)));

static __device__ __forceinline__ unsigned short f2bf(float f) {
  union { float f; unsigned int u; } v; v.f = f;
  unsigned int r = v.u + 0x7fffu + ((v.u >> 16) & 1u);
  return (unsigned short)(r >> 16);
}
static __device__ __forceinline__ float bf2f(unsigned short h) {
  union { unsigned int u; float f; } v; v.u = ((unsigned int)h) << 16;
  return v.f;
}

// tanh-form GELU (branchless). |err vs erf-GELU| <= ~3e-3/elem, diluted by @W2.
static __device__ __forceinline__ float gelu_f(float v) {
  const float v2 = v * v;
  const float w = v * (0.7978845608f + 0.0356774081f * v2);
  const float a = fminf(w * 2.8853900818f, 126.0f);
  const float u = exp2f(a);
  return v * u / (u + 1.0f);
}

static __device__ __forceinline__ char q8(float v, float inv) {
  int q = __float2int_rn(v * inv);
  q = q > 127 ? 127 : (q < -127 ? -127 : q);
  return (char)q;
}

__device__ __forceinline__ void gload_lds16(const void* g, void* l) {
  __builtin_amdgcn_global_load_lds((const __attribute__((address_space(1))) void*)g,
                                   (__attribute__((address_space(3))) void*)l, 16, 0, 0);
}

#define H1S   (3.0f / 127.0f)
#define IH1S  (127.0f / 3.0f)

// ---------------- tiny precompute kernels ----------------

__global__ __launch_bounds__(256) void pre_kv(const float* __restrict__ aux,
                                              const float* __restrict__ Wkv,
                                              const float* __restrict__ bkv,
                                              float* __restrict__ kv) {
  const int g = blockIdx.x * 256 + threadIdx.x;   // 65536 = 64 * 1024
  const int j = g >> 10, cc = g & 1023;
  float s = bkv[cc];
  for (int i = 0; i < C_; ++i) s += aux[j * C_ + i] * Wkv[i * (2 * C_) + cc];
  kv[g] = s;
}

// col = h*64 + j  (softmax-contiguous layout)
__global__ __launch_bounds__(256) void pre_MT(const float* __restrict__ Wq,
                                              const float* __restrict__ bq,
                                              const float* __restrict__ kv,
                                              unsigned short* __restrict__ MT,
                                              float* __restrict__ cbias) {
  const int col = blockIdx.x;                 // 0..511
  const int h = col >> 6, j = col & 63;
  const float* kvp = kv + j * 1024 + h * 64;
  for (int c = threadIdx.x; c < C_; c += 256) {
    float s = 0.f;
    for (int d = 0; d < 64; ++d) s += Wq[(size_t)c * C_ + h * 64 + d] * kvp[d];
    MT[(size_t)col * C_ + c] = f2bf(0.125f * s);   // scale^2 = (C/H)^-0.5
  }
  if (threadIdx.x == 0) {
    float s = 0.f;
    for (int d = 0; d < 64; ++d) s += bq[h * 64 + d] * kvp[d];
    cbias[col] = 0.125f * s;
  }
}

__global__ __launch_bounds__(256) void pre_VoT(const float* __restrict__ Wo,
                                               const float* __restrict__ kv,
                                               unsigned short* __restrict__ VoT) {
  const int cp = blockIdx.x;                  // output channel
  for (int col = threadIdx.x; col < 512; col += 256) {
    const int h = col >> 6, j = col & 63;
    float s = 0.f;
    for (int d = 0; d < 64; ++d)
      s += kv[j * 1024 + 512 + h * 64 + d] * Wo[(size_t)(h * 64 + d) * C_ + cp];
    VoT[(size_t)cp * 512 + col] = f2bf(s);
  }
}

// per-output-col absmax scales: one BLOCK per column, 256 threads, wave+LDS reduce.
// (R10 bug: grid of 2/6 blocks -> 364 us serial kernel.)
template<int ROWS, int NCOLS>
__global__ __launch_bounds__(256) void pre_wscale(const float* __restrict__ W,
                                                  float* __restrict__ ws) {
  __shared__ unsigned int red;
  const int n = blockIdx.x;                    // column
  const int tid = threadIdx.x;
  if (tid == 0) red = 0;
  __syncthreads();
  float amax = 0.f;
  for (int k = tid; k < ROWS; k += 256)
    amax = fmaxf(amax, fabsf(W[(size_t)k * NCOLS + n]));
#pragma unroll
  for (int off = 1; off < 64; off <<= 1)
    amax = fmaxf(amax, __shfl_xor(amax, off));
  if ((tid & 63) == 0) atomicMax(&red, __float_as_uint(amax));
  __syncthreads();
  if (tid == 0) ws[n] = fmaxf(__uint_as_float(red), 1e-20f) / 127.0f;
}

__global__ __launch_bounds__(256) void pre_W1Q(const float* __restrict__ W1,
                                               const float* __restrict__ w1s,
                                               char* __restrict__ W1Q) {
  const int g = blockIdx.x * 256 + threadIdx.x;    // 1536*512
  const int n = g >> 9, k = g & 511;
  W1Q[g] = q8(W1[(size_t)k * I_ + n], 1.0f / w1s[n]);
}

__global__ __launch_bounds__(256) void pre_W2Q(const float* __restrict__ W2,
                                               const float* __restrict__ w2s,
                                               char* __restrict__ W2Q) {
  const int g = blockIdx.x * 256 + threadIdx.x;    // 512*1536
  const int n = g / 1536, k = g - n * 1536;
  W2Q[g] = q8(W2[(size_t)k * C_ + n], 1.0f / w2s[n]);
}

// ---------------- x (B,C,T) -> xt bf16 (B*T, C) ----------------

__global__ __launch_bounds__(256) void xt_kernel(const float* __restrict__ x,
                                                 unsigned short* __restrict__ xt) {
  __shared__ float ld[64][65];
  const int tid = threadIdx.x;
  const int t0 = blockIdx.x * 64, c0 = blockIdx.y * 64, b = blockIdx.z;
  for (int idx = tid; idx < 4096; idx += 256) {
    const int r = idx >> 6, cc = idx & 63;
    ld[r][cc] = x[((size_t)(b * C_ + c0 + r)) * T_ + t0 + cc];
  }
  __syncthreads();
  for (int idx = tid; idx < 4096; idx += 256) {
    const int tr = idx >> 6, cl = idx & 63;
    xt[((size_t)(b * T_ + t0 + tr)) * C_ + c0 + cl] = f2bf(ld[cl][tr]);
  }
}

// ---------------- GEMM A (m97 structure, k-major LDS chunks): attention GEMMs ----------------
// EPI 1: per-head softmax epilogue -> outU (P bf16, stride N). bias = cb.
// EPI 4: rs[(b*C+c)*T+t] = bf16( bf2f(resU[r*512+c]) + acc + bias[c] )   (resU = xt)
template<int N, int K, int NCOL, int EPI>
__global__ __launch_bounds__(256) void gemm_mfma(const unsigned short* __restrict__ A,
                                                 const unsigned short* __restrict__ Bt,
                                                 const float* __restrict__ bias,
                                                 unsigned short* __restrict__ outU,
                                                 const unsigned short* __restrict__ resU,
                                                 float* __restrict__ outF) {
  __shared__ __align__(16) unsigned short lA[128 * 32];
  __shared__ __align__(16) unsigned short lB[128 * 32];
  const int q = gridDim.x >> 3;
  const int wgid = (blockIdx.x & 7) * q + (blockIdx.x >> 3);
  const int row0 = (wgid / NCOL) * 128;
  const int col0 = (wgid % NCOL) * 128;
  const int tid = threadIdx.x;
  const int w = tid >> 6, lane = tid & 63;
  const int wr = (w >> 1) * 64, wc = (w & 1) * 64;
  const int c1 = tid, c2 = tid + 256;

  const f32x4 zero4 = {0.f, 0.f, 0.f, 0.f};
  f32x4 acc[4][4];
#pragma unroll
  for (int m = 0; m < 4; ++m)
#pragma unroll
    for (int n = 0; n < 4; ++n) acc[m][n] = zero4;

  const size_t aBase = (size_t)row0 * K;
  const size_t bBase = (size_t)col0 * K;
  const int lrow = lane & 15, lg = lane >> 4;

  for (int k0 = 0; k0 < K; k0 += 32) {
    gload_lds16(A + aBase + (size_t)(c1 & 127) * K + k0 + (c1 >> 7) * 8, (char*)lA + c1 * 16);
    gload_lds16(A + aBase + (size_t)(c2 & 127) * K + k0 + (c2 >> 7) * 8, (char*)lA + c2 * 16);
    gload_lds16(Bt + bBase + (size_t)(c1 & 127) * K + k0 + (c1 >> 7) * 8, (char*)lB + c1 * 16);
    gload_lds16(Bt + bBase + (size_t)(c2 & 127) * K + k0 + (c2 >> 7) * 8, (char*)lB + c2 * 16);
    __syncthreads();
    short8 av[4], bv[4];
#pragma unroll
    for (int m = 0; m < 4; ++m)
      av[m] = *(const short8*)&lA[(lg * 128 + wr + m * 16 + lrow) * 8];
#pragma unroll
    for (int n = 0; n < 4; ++n)
      bv[n] = *(const short8*)&lB[(lg * 128 + wc + n * 16 + lrow) * 8];
#pragma unroll
    for (int m = 0; m < 4; ++m)
#pragma unroll
      for (int n = 0; n < 4; ++n)
        acc[m][n] = __builtin_amdgcn_mfma_f32_16x16x32_bf16(av[m], bv[n], acc[m][n], 0, 0, 0);
    __syncthreads();
  }

  if (EPI == 1) {
    float cbv[4];
#pragma unroll
    for (int n = 0; n < 4; ++n) cbv[n] = bias[col0 + wc + n * 16 + lrow];
#pragma unroll
    for (int m = 0; m < 4; ++m) {
#pragma unroll
      for (int i = 0; i < 4; ++i) {
        float e0 = acc[m][0][i] + cbv[0];
        float e1 = acc[m][1][i] + cbv[1];
        float e2 = acc[m][2][i] + cbv[2];
        float e3 = acc[m][3][i] + cbv[3];
        float mx = fmaxf(fmaxf(e0, e1), fmaxf(e2, e3));
        mx = fmaxf(mx, __shfl_xor(mx, 1));
        mx = fmaxf(mx, __shfl_xor(mx, 2));
        mx = fmaxf(mx, __shfl_xor(mx, 4));
        mx = fmaxf(mx, __shfl_xor(mx, 8));
        e0 = __expf(e0 - mx); e1 = __expf(e1 - mx);
        e2 = __expf(e2 - mx); e3 = __expf(e3 - mx);
        float s = e0 + e1 + e2 + e3;
        s += __shfl_xor(s, 1);
        s += __shfl_xor(s, 2);
        s += __shfl_xor(s, 4);
        s += __shfl_xor(s, 8);
        const float inv = 1.0f / s;
        const size_t rb = (size_t)(row0 + wr + m * 16 + (lane >> 4) * 4 + i) * N;
        outU[rb + col0 + wc + 0 * 16 + lrow] = f2bf(e0 * inv);
        outU[rb + col0 + wc + 1 * 16 + lrow] = f2bf(e1 * inv);
        outU[rb + col0 + wc + 2 * 16 + lrow] = f2bf(e2 * inv);
        outU[rb + col0 + wc + 3 * 16 + lrow] = f2bf(e3 * inv);
      }
    }
    return;
  }

#pragma unroll
  for (int m = 0; m < 4; ++m) {
    const int r0 = row0 + wr + m * 16 + ((lane >> 4) << 2);
#pragma unroll
    for (int n = 0; n < 4; ++n) {
      const int c = col0 + wc + n * 16 + lrow;
      const float bb = bias[c];
      const int bidx = r0 >> 12;          // T = 4096
      const int t = r0 & 4095;
      const size_t addr = ((size_t)(bidx * C_ + c)) * T_ + t;
      us4 o;
#pragma unroll
      for (int i = 0; i < 4; ++i)
        o[i] = f2bf(bf2f(resU[(size_t)(r0 + i) * 512 + c]) + acc[m][n][i] + bb);
      *(us4*)&outU[addr] = o;
    }
  }
}

// ---------------- GEMM B: int8 256x256 8-phase (MLP GEMMs), R5 schedule verbatim ----------------
// mfma_i32_16x16x64_i8: K=64/inst, 16-byte frags -> R5's 16B-chunk LDS layout, staging
// lambda and vmcnt accounting unchanged; K-tile = 128 i8 -> phase count halves vs bf16.
// EPI 3: H1Q = i8( gelu(acc*rowS[r]*colS[c] + b1[c]) / H1S )
// EPI 5: outF = bf2f(rs) + acc*(H1S*colS[c]) + b2[c]

#define LOAD_AVQ(d, mh) {                                                     \
  const char* abase = lds + ((d)*32768 + (mh)*16384);                         \
  _Pragma("unroll")                                                           \
  for (int ks = 0; ks < 2; ++ks) {                                            \
    const int kc = ks * 4 + lg;                                               \
    _Pragma("unroll")                                                         \
    for (int mf = 0; mf < 4; ++mf)                                            \
      av[ks][mf] = *(const i32x4*)(abase + (size_t)(kc*128 + wm*64 + mf*16 + lrow)*16); \
  } }

#define LOAD_BVQ(d, nh, DST) {                                                \
  const char* bbase = lds + (65536 + (d)*32768 + (nh)*16384);                 \
  _Pragma("unroll")                                                           \
  for (int ks = 0; ks < 2; ++ks) {                                            \
    const int kc = ks * 4 + lg;                                               \
    _Pragma("unroll")                                                         \
    for (int nf = 0; nf < 2; ++nf)                                            \
      DST[ks][nf] = *(const i32x4*)(bbase + (size_t)(kc*128 + wn*32 + nf*16 + lrow)*16); \
  } }

#define PHXQ(LOADS, STAGE_STMT, VM_STMT, MH, NH, BV) {                        \
  LOADS;                                                                      \
  STAGE_STMT;                                                                 \
  VM_STMT;                                                                    \
  __builtin_amdgcn_s_barrier();                                               \
  __builtin_amdgcn_s_setprio(1);                                              \
  _Pragma("unroll")                                                           \
  for (int mf = 0; mf < 4; ++mf)                                              \
    _Pragma("unroll")                                                         \
    for (int nf = 0; nf < 2; ++nf) {                                          \
      acc[(MH)*4+mf][(NH)*2+nf] = __builtin_amdgcn_mfma_i32_16x16x64_i8(       \
          av[0][mf], BV[0][nf], acc[(MH)*4+mf][(NH)*2+nf], 0, 0, 0);          \
      acc[(MH)*4+mf][(NH)*2+nf] = __builtin_amdgcn_mfma_i32_16x16x64_i8(       \
          av[1][mf], BV[1][nf], acc[(MH)*4+mf][(NH)*2+nf], 0, 0, 0);          \
    }                                                                         \
  __builtin_amdgcn_s_setprio(0);                                              \
  asm volatile("s_waitcnt lgkmcnt(0)" ::: "memory");                          \
  __builtin_amdgcn_s_barrier();                                               \
}

#define NOPS ((void)0)

template<int N, int K, int NCOL, int EPI>
__global__ __launch_bounds__(512, 2) void gemm8q(const char* __restrict__ A,
                                                 const char* __restrict__ Bt,
                                                 const float* __restrict__ rowS,
                                                 const float* __restrict__ colS,
                                                 const float* __restrict__ bias,
                                                 char* __restrict__ outQ,
                                                 const unsigned short* __restrict__ resU,
                                                 float* __restrict__ outF) {
  __shared__ __align__(16) char lds[131072];
  const int tid = threadIdx.x;
  const int w = tid >> 6, lane = tid & 63;
  const int wm = w >> 2, wn = w & 3;
  const int lrow = lane & 15, lg = lane >> 4;
  const int q8g = gridDim.x >> 3;
  const int wgid = (blockIdx.x & 7) * q8g + (blockIdx.x >> 3);
  const int row0 = (wgid / NCOL) * 256;
  const int col0 = (wgid % NCOL) * 256;

  auto stageA = [&](int kt, int h) {
    char* base = lds + ((kt & 1) * 32768 + h * 16384);
    const char* gsrc = A + (size_t)(row0 + h * 128) * K + kt * 128;
#pragma unroll
    for (int s = 0; s < 2; ++s) {
      const int qq = w * 128 + s * 64 + lane;
      gload_lds16(gsrc + (size_t)(qq & 127) * K + (qq >> 7) * 16, base + qq * 16);
    }
  };
  auto stageB = [&](int kt, int h) {
    char* base = lds + (65536 + (kt & 1) * 32768 + h * 16384);
    const char* gsrc = Bt + (size_t)(col0 + h * 128) * K + kt * 128;
#pragma unroll
    for (int s = 0; s < 2; ++s) {
      const int qq = w * 128 + s * 64 + lane;
      gload_lds16(gsrc + (size_t)(qq & 127) * K + (qq >> 7) * 16, base + qq * 16);
    }
  };

  const i32x4 zero4 = {0, 0, 0, 0};
  i32x4 acc[8][4];
#pragma unroll
  for (int m = 0; m < 8; ++m)
#pragma unroll
    for (int n = 0; n < 4; ++n) acc[m][n] = zero4;

  i32x4 av[2][4], bv0[2][2], bv1[2][2];

  const int KT = K / 128;     // G3: 4, G4: 12 (both even)

  // prologue: tile0 fully, tile1 halves A0,B0
  stageA(0, 0); stageA(0, 1); stageB(0, 0); stageB(0, 1);
  stageA(1, 0); stageB(1, 0);
  asm volatile("s_waitcnt vmcnt(4)" ::: "memory");
  __builtin_amdgcn_s_barrier();

  for (int i = 0; i < KT / 2; ++i) {
    const int t1 = 2 * i + 1, t2 = 2 * i + 2, t3 = 2 * i + 3;
    // tile 2i (buf 0)
    PHXQ(LOAD_AVQ(0, 0); LOAD_BVQ(0, 0, bv0), { stageA(t1, 1); }, NOPS, 0, 0, bv0);
    PHXQ(LOAD_BVQ(0, 1, bv1),                 { stageB(t1, 1); }, NOPS, 0, 1, bv1);
    PHXQ(LOAD_AVQ(0, 1),                      { if (t2 < KT) stageA(t2, 0); }, NOPS, 1, 1, bv1);
    PHXQ(NOPS,                                { if (t2 < KT) stageB(t2, 0); },
        { if (t2 < KT) { asm volatile("s_waitcnt vmcnt(4)" ::: "memory"); }
          else         { asm volatile("s_waitcnt vmcnt(0)" ::: "memory"); } },
        1, 0, bv0);
    // tile 2i+1 (buf 1)
    PHXQ(LOAD_AVQ(1, 0); LOAD_BVQ(1, 0, bv0), { if (t2 < KT) stageA(t2, 1); }, NOPS, 0, 0, bv0);
    PHXQ(LOAD_BVQ(1, 1, bv1),                 { if (t2 < KT) stageB(t2, 1); }, NOPS, 0, 1, bv1);
    PHXQ(LOAD_AVQ(1, 1),                      { if (t3 < KT) stageA(t3, 0); }, NOPS, 1, 1, bv1);
    PHXQ(NOPS,                                { if (t3 < KT) stageB(t3, 0); },
        { asm volatile("s_waitcnt vmcnt(4)" ::: "memory"); },
        1, 0, bv0);
  }

  // epilogue
#pragma unroll
  for (int mf = 0; mf < 8; ++mf) {
    const int r0 = row0 + (mf >> 2) * 128 + wm * 64 + (mf & 3) * 16 + lg * 4;
#pragma unroll
    for (int nf = 0; nf < 4; ++nf) {
      const int c = col0 + (nf >> 1) * 128 + wn * 32 + (nf & 1) * 16 + lrow;
      const float bb = bias[c];
      const float sc = colS[c];
      if (EPI == 3) {
#pragma unroll
        for (int i = 0; i < 4; ++i) {
          const float v = (float)acc[mf][nf][i] * (rowS[r0 + i] * sc) + bb;
          const float g = gelu_f(v);
          outQ[(size_t)(r0 + i) * N + c] = q8(fminf(fmaxf(g, -3.0f), 3.0f), IH1S);
        }
      } else {  // EPI == 5
        const float ds = H1S * sc;
        const int bidx = r0 >> 12;
        const int t = r0 & 4095;
        const size_t addr = ((size_t)(bidx * C_ + c)) * T_ + t;
        const us4 rv = *(const us4*)&resU[addr];
        f32x4 o;
#pragma unroll
        for (int i = 0; i < 4; ++i) o[i] = bf2f(rv[i]) + (float)acc[mf][nf][i] * ds + bb;
        *(f32x4*)&outF[addr] = o;
      }
    }
  }
}

// ---------------- fused conv1d(k=7,p=3) + AdaLayerNorm -> int8 yln + per-token scale ----------------

__global__ __launch_bounds__(256) void convq_kernel(
    const unsigned short* __restrict__ rs,
    const float* __restrict__ dww,
    const float* __restrict__ dwb,
    const int* __restrict__ ids,
    const float* __restrict__ sce,
    const float* __restrict__ she,
    char* __restrict__ ylnq,
    float* __restrict__ yscale) {
  __shared__ float cbuf[16 * 520];
  const int tid = threadIdx.x;
  const int t0 = blockIdx.x * 16;
  const int b = blockIdx.y;
#pragma unroll
  for (int cc = 0; cc < 2; ++cc) {
    const int c = cc * 256 + tid;
    float f[24];
#pragma unroll
    for (int j = 0; j < 6; ++j) {
      const int t = t0 - 4 + j * 4;
      if (t >= 0 && t < T_) {
        const us4 v = *(const us4*)&rs[((size_t)(b * C_ + c)) * T_ + t];
#pragma unroll
        for (int i = 0; i < 4; ++i) f[j * 4 + i] = bf2f(v[i]);
      } else {
#pragma unroll
        for (int i = 0; i < 4; ++i) f[j * 4 + i] = 0.f;
      }
    }
    float wk[7];
#pragma unroll
    for (int k = 0; k < 7; ++k) wk[k] = dww[c * 7 + k];
    const float bb = dwb[c];
#pragma unroll
    for (int tt = 0; tt < 16; ++tt) {
      float s = bb;
#pragma unroll
      for (int k = 0; k < 7; ++k) s += f[tt + 1 + k] * wk[k];
      cbuf[tt * 520 + c] = s;
    }
  }
  __syncthreads();
  const int lane = tid & 63, w = tid >> 6;
  const int id = ids[b];
#pragma unroll
  for (int tt = 0; tt < 4; ++tt) {
    const int t = w * 4 + tt;
    const f32x4 v0 = *(const f32x4*)&cbuf[t * 520 + lane * 8];
    const f32x4 v1 = *(const f32x4*)&cbuf[t * 520 + lane * 8 + 4];
    float s = 0.f, sq = 0.f;
#pragma unroll
    for (int i = 0; i < 4; ++i) { s += v0[i]; sq += v0[i] * v0[i]; }
#pragma unroll
    for (int i = 0; i < 4; ++i) { s += v1[i]; sq += v1[i] * v1[i]; }
#pragma unroll
    for (int off = 1; off < 64; off <<= 1) {
      s += __shfl_xor(s, off);
      sq += __shfl_xor(sq, off);
    }
    const float mean = s * (1.0f / 512.0f);
    const float var = sq * (1.0f / 512.0f) - mean * mean;
    const float rstd = rsqrtf(var + 1e-6f);
    const f32x4 sc0 = *(const f32x4*)&sce[id * C_ + lane * 8];
    const f32x4 sc1 = *(const f32x4*)&sce[id * C_ + lane * 8 + 4];
    const f32x4 sh0 = *(const f32x4*)&she[id * C_ + lane * 8];
    const f32x4 sh1 = *(const f32x4*)&she[id * C_ + lane * 8 + 4];
    float y[8];
    float amax = 0.f;
#pragma unroll
    for (int i = 0; i < 4; ++i) {
      y[i]     = (v0[i] - mean) * rstd * sc0[i] + sh0[i];
      y[4 + i] = (v1[i] - mean) * rstd * sc1[i] + sh1[i];
    }
#pragma unroll
    for (int i = 0; i < 8; ++i) amax = fmaxf(amax, fabsf(y[i]));
#pragma unroll
    for (int off = 1; off < 64; off <<= 1) amax = fmaxf(amax, __shfl_xor(amax, off));
    amax = fmaxf(amax, 1e-20f);
    const float inv = 127.0f / amax;
    const int tg = b * T_ + t0 + t;
    char8v o;
#pragma unroll
    for (int i = 0; i < 8; ++i) o[i] = q8(y[i], inv);
    *(char8v*)&ylnq[(size_t)tg * C_ + lane * 8] = o;
    if (lane == 0) yscale[tg] = amax * (1.0f / 127.0f);
  }
}

// ---------------- launch ----------------

extern "C" void kernel_launch(void* const* d_in, const int* in_sizes, int n_in,
                              void* d_out, int out_size, void* d_ws, size_t ws_size,
                              hipStream_t stream) {
  const float* x   = (const float*)d_in[0];
  const int*   ids = (const int*)d_in[1];
  const float* Wq  = (const float*)d_in[2];
  const float* bq  = (const float*)d_in[3];
  const float* Wkv = (const float*)d_in[4];
  const float* bkv = (const float*)d_in[5];
  const float* Wo  = (const float*)d_in[6];
  const float* bo  = (const float*)d_in[7];
  const float* dww = (const float*)d_in[8];
  const float* dwb = (const float*)d_in[9];
  const float* sce = (const float*)d_in[10];
  const float* she = (const float*)d_in[11];
  const float* W1  = (const float*)d_in[12];
  const float* b1  = (const float*)d_in[13];
  const float* W2  = (const float*)d_in[14];
  const float* b2  = (const float*)d_in[15];
  const float* aux = (const float*)d_in[16];
  float* out = (float*)d_out;

  char* ws = (char*)d_ws;
  unsigned short* xt   = (unsigned short*)(ws + 0);              // 64 MB
  unsigned short* P    = (unsigned short*)(ws + (64u  << 20));   // 64 MB
  char*           ylnq = (char*)(ws + (64u << 20));              // 32 MB (overlays P; P dead)
  float*          ysc  = (float*)(ws + (100u << 20));            // 256 KB
  unsigned short* rs   = (unsigned short*)(ws + (128u << 20));   // 64 MB (bf16)
  char*           H1Q  = (char*)(ws + (192u << 20));             // 96 MB (i8)
  char* sm = ws + (384u << 20);
  float*          kv   = (float*)(sm);                           // 256 KB
  float*          cb   = (float*)(sm + 262144);                  // 2 KB
  unsigned short* MT   = (unsigned short*)(sm + 264192);         // 512 KB
  unsigned short* VoT  = (unsigned short*)(sm + 788480);         // 512 KB
  char*           W1Q  = (char*)(sm + 1312768);                  // 768 KB
  char*           W2Q  = (char*)(sm + 2099200);                  // 768 KB
  float*          w1s  = (float*)(sm + 2885632);                 // 6 KB
  float*          w2s  = (float*)(sm + 2891776);                 // 2 KB

  pre_kv <<<dim3(256),  dim3(256), 0, stream>>>(aux, Wkv, bkv, kv);
  pre_MT <<<dim3(512),  dim3(256), 0, stream>>>(Wq, bq, kv, MT, cb);
  pre_VoT<<<dim3(512),  dim3(256), 0, stream>>>(Wo, kv, VoT);
  pre_wscale<512, 1536><<<dim3(1536), dim3(256), 0, stream>>>(W1, w1s);
  pre_wscale<1536, 512><<<dim3(512),  dim3(256), 0, stream>>>(W2, w2s);
  pre_W1Q<<<dim3(3072), dim3(256), 0, stream>>>(W1, w1s, W1Q);
  pre_W2Q<<<dim3(3072), dim3(256), 0, stream>>>(W2, w2s, W2Q);
  xt_kernel<<<dim3(64, 8, 16), dim3(256), 0, stream>>>(x, xt);

  // attention as two m97-structure GEMMs with fused softmax / residual epilogues
  gemm_mfma<512, 512, 4, 1><<<dim3(2048), dim3(256), 0, stream>>>(
      xt, MT, cb, P, nullptr, nullptr);
  gemm_mfma<512, 512, 4, 4><<<dim3(2048), dim3(256), 0, stream>>>(
      P, VoT, bo, rs, xt, nullptr);
  convq_kernel<<<dim3(256, 16), dim3(256), 0, stream>>>(rs, dww, dwb, ids, sce, she,
                                                        ylnq, ysc);
  // MLP as two int8 256^2 8-phase GEMMs (R5 schedule, half the phases)
  gemm8q<1536, 512, 6, 3><<<dim3(1536), dim3(512), 0, stream>>>(
      ylnq, W1Q, ysc, w1s, b1, H1Q, nullptr, nullptr);
  gemm8q<512, 1536, 2, 5><<<dim3(512), dim3(512), 0, stream>>>(
      H1Q, W2Q, nullptr, w2s, b2, nullptr, rs, out);
}